// Round 4
// baseline (601.835 us; speedup 1.0000x reference)
//
#include <hip/hip_runtime.h>
#include <hip/hip_bf16.h>
#include <math.h>

#define BB 32
#define SS 4096
#define EE 512
#define AA 512

typedef short bf16x8 __attribute__((ext_vector_type(8)));
typedef float f32x4 __attribute__((ext_vector_type(4)));
typedef unsigned short u16x4 __attribute__((ext_vector_type(4)));

__device__ __forceinline__ unsigned short f2bf(float f) {
  unsigned int u = __float_as_uint(f);
  u += 0x7fffu + ((u >> 16) & 1u);   // RNE (finite normals)
  return (unsigned short)(u >> 16);
}

__device__ __forceinline__ float bf2f(unsigned short s) {
  return __uint_as_float(((unsigned int)s) << 16);
}

__device__ __forceinline__ float tanh_fast(float x) {
  return 1.f - 2.f / (__expf(2.f * x) + 1.f);
}

// Merged prologue kernel, role by blockIdx.x:
//   [0,32)    : query  q[b][a] = sum_e h[b][e]*Wh[e][a]
//   [32,96)   : Wst[a][e] = bf16(Ws[e][a])  (LDS-tiled transpose)
//   [96,2144) : encb = bf16(enc)  -- pure streaming convert, grid-stride,
//               continuous-issue (the 6.3 TB/s copy-ubench pattern)
__global__ __launch_bounds__(512) void prep_kernel(
    const float* __restrict__ h, const float* __restrict__ Wh,
    const float* __restrict__ Ws, const float* __restrict__ enc,
    float* __restrict__ q, unsigned short* __restrict__ Wst,
    unsigned short* __restrict__ encb, int do_conv) {
  __shared__ __align__(16) unsigned char plds[64 * 65 * 2];
  const int blk = blockIdx.x;
  const int t = threadIdx.x;
  if (blk < 32) {                       // ---- query ----
    float* hrow = (float*)plds;
    const int b = blk;
    hrow[t] = h[b * EE + t];
    __syncthreads();
    float a = 0.f;
#pragma unroll 8
    for (int e = 0; e < EE; ++e) a += hrow[e] * Wh[e * AA + t];
    q[b * AA + t] = a;
  } else if (blk < 96) {                // ---- Wst transpose ----
    unsigned short(*tile)[65] = (unsigned short(*)[65])plds;
    const int idx = blk - 32;
    const int a0 = (idx & 7) * 64, e0 = (idx >> 3) * 64;
    const int c = t & 63, r = t >> 6;
#pragma unroll
    for (int i = 0; i < 8; ++i) {
      int e = r + i * 8;
      tile[c][e] = f2bf(Ws[(size_t)(e0 + e) * AA + a0 + c]);
    }
    __syncthreads();
#pragma unroll
    for (int i = 0; i < 8; ++i) {
      int a = r + i * 8;
      Wst[(size_t)(a0 + a) * EE + e0 + c] = tile[a][c];
    }
  } else if (do_conv) {                 // ---- enc fp32 -> bf16 ----
    const size_t ci = (size_t)(blk - 96);
    const float4* s4 = (const float4*)enc;
    bf16x8* d8 = (bf16x8*)encb;
#pragma unroll
    for (int it = 0; it < 8; ++it) {
      size_t g = ci * 4096 + (size_t)it * 512 + t;   // 8-elem group index
      float4 x = s4[g * 2];
      float4 y = s4[g * 2 + 1];
      bf16x8 vv;
      vv[0] = (short)f2bf(x.x); vv[1] = (short)f2bf(x.y);
      vv[2] = (short)f2bf(x.z); vv[3] = (short)f2bf(x.w);
      vv[4] = (short)f2bf(y.x); vv[5] = (short)f2bf(y.y);
      vv[6] = (short)f2bf(y.z); vv[7] = (short)f2bf(y.w);
      d8[g] = vv;
    }
  }
}

// Fused: per block (chunk=blockIdx.x -> 64 s-rows, b=blockIdx.y), 512 threads.
// 2 blocks/CU (16 waves). Staging from pre-converted bf16 (L2/L3-hot),
// 16 B/thread/chunk, depth-3 register pipeline; MFMA B-panel loaded in-loop.
__global__ __launch_bounds__(512, 4) void fused_kernel(
    const float* __restrict__ enc, const unsigned short* __restrict__ encb,
    const unsigned short* __restrict__ Wst, const float* __restrict__ q,
    const float* __restrict__ v, const int* __restrict__ mask,
    float* __restrict__ rawscore,   // -> attn region of d_out
    float* __restrict__ ctxp,       // [32][64][512]
    float* __restrict__ mbuf,       // [32][64]
    int use_bf) {
  __shared__ __align__(16) unsigned short Atile[64 * 512];  // 64 KB
  __shared__ float spart[8][64];
  __shared__ float wrow[64];
  const int b = blockIdx.y, chunk = blockIdx.x;
  const int s0 = chunk * 64;
  const int tid = threadIdx.x;
  const int w = tid >> 6, lane = tid & 63;
  const int quad = lane >> 4, l16 = lane & 15;
  const int n0 = w * 64;            // 8 waves x 64 N-cols

  // bf16-staging geometry: thread owns (row = tid>>3, piece = tid&7)
  const int brow = tid >> 3, bpiece = tid & 7;
  const bf16x8* gB =
      (const bf16x8*)(encb + ((size_t)b * SS + s0 + brow) * EE) + bpiece;
  unsigned short* stB_row = &Atile[brow * 512];

  // fp32 fallback geometry (R1): rows {rbase, rbase+32}, float4 c4
  const int rbase = tid >> 4;
  const int c4 = tid & 15;
  const int sw3 = (rbase & 7) << 3;
  const float4* src4 = (const float4*)(enc + ((size_t)b * SS + s0) * EE);
  const float4* g0 = src4 + rbase * 128 + c4;
  const float4* g1 = g0 + 32 * 128;
  unsigned short* st0 = &Atile[rbase * 512 + ((c4 * 4) ^ sw3)];
  unsigned short* st1 = st0 + 32 * 512;

  const unsigned short* wb = Wst + (size_t)(n0 + l16) * EE + quad * 8;

  f32x4 acc[4][4];
#pragma unroll
  for (int m = 0; m < 4; ++m)
#pragma unroll
    for (int j = 0; j < 4; ++j) acc[m][j] = (f32x4){0.f, 0.f, 0.f, 0.f};

  bf16x8 rbB[3];
  float4 rb[2][2];
  if (use_bf) {
    rbB[0] = gB[0]; rbB[1] = gB[8]; rbB[2] = gB[16];
  } else {
    rb[0][0] = g0[0]; rb[0][1] = g1[0];
  }

#pragma unroll
  for (int c = 0; c < 8; ++c) {
    if (use_bf) {
      // store chunk c (16 B), swizzled; issue chunk c+3
      *(bf16x8*)&stB_row[(((c * 8 + bpiece) ^ (brow & 7)) * 8)] = rbB[c % 3];
      if (c + 3 < 8) rbB[(c + 3) % 3] = gB[(c + 3) * 8];
    } else {
      const int cur = c & 1;
      float4 x = rb[cur][0];
      u16x4 p;
      p.x = f2bf(x.x); p.y = f2bf(x.y); p.z = f2bf(x.z); p.w = f2bf(x.w);
      *(u16x4*)(st0 + c * 64) = p;
      float4 y = rb[cur][1];
      u16x4 p2;
      p2.x = f2bf(y.x); p2.y = f2bf(y.y); p2.z = f2bf(y.z); p2.w = f2bf(y.w);
      *(u16x4*)(st1 + c * 64) = p2;
      if (c + 1 < 8) {
        rb[cur ^ 1][0] = g0[(c + 1) * 16];
        rb[cur ^ 1][1] = g1[(c + 1) * 16];
      }
    }
    asm volatile("s_waitcnt lgkmcnt(0)" ::: "memory");  // ds_writes committed
    __builtin_amdgcn_s_barrier();                        // no vmcnt drain
    // ---- MFMA over k in [c*64, c*64+64) ----
#pragma unroll
    for (int kk = 0; kk < 2; ++kk) {
      const int k0 = c * 64 + kk * 32;
      bf16x8 aF[4];
#pragma unroll
      for (int m = 0; m < 4; ++m) {
        const int row = m * 16 + l16;
        aF[m] = *(const bf16x8*)&Atile[row * 512 +
                                       ((k0 + quad * 8) ^ ((row & 7) << 3))];
      }
#pragma unroll
      for (int j = 0; j < 4; ++j) {
        bf16x8 bF = *(const bf16x8*)&wb[(size_t)j * 16 * EE + k0];
#pragma unroll
        for (int m = 0; m < 4; ++m)
          acc[m][j] = __builtin_amdgcn_mfma_f32_16x16x32_bf16(aF[m], bF,
                                                              acc[m][j], 0, 0, 0);
      }
    }
  }

  // ---- epilogue: tanh + v-weighted accumulate ----
  float srow[4][4];
#pragma unroll
  for (int m = 0; m < 4; ++m)
#pragma unroll
    for (int r = 0; r < 4; ++r) srow[m][r] = 0.f;
#pragma unroll
  for (int j = 0; j < 4; ++j) {
    float qn = q[b * AA + n0 + j * 16 + l16];
    float vn = v[n0 + j * 16 + l16];
#pragma unroll
    for (int m = 0; m < 4; ++m)
#pragma unroll
      for (int r = 0; r < 4; ++r)
        srow[m][r] += tanh_fast(qn + acc[m][j][r]) * vn;
  }
#pragma unroll
  for (int m = 0; m < 4; ++m)
#pragma unroll
    for (int r = 0; r < 4; ++r) {
      float s = srow[m][r];
      s += __shfl_xor(s, 1, 64);
      s += __shfl_xor(s, 2, 64);
      s += __shfl_xor(s, 4, 64);
      s += __shfl_xor(s, 8, 64);
      if (l16 == 0) spart[w][m * 16 + quad * 4 + r] = s;
    }
  __syncthreads();

  // ---- Phase C: masked scores, chunk max, exp weights ----
  if (tid < 64) {
    float raw = 0.f;
#pragma unroll
    for (int ww = 0; ww < 8; ++ww) raw += spart[ww][tid];
    float sc = mask[(size_t)b * SS + s0 + tid] ? -1e9f : raw;
    rawscore[(size_t)b * SS + s0 + tid] = sc;
    float mx = sc;
    for (int off = 1; off < 64; off <<= 1)
      mx = fmaxf(mx, __shfl_xor(mx, off, 64));
    wrow[tid] = __expf(sc - mx);
    if (tid == 0) mbuf[b * 64 + chunk] = mx;
  }
  __syncthreads();

  // ---- Phase D: ctx partial, one e-column per thread ----
  {
    const int e = tid;
    float a = 0.f;
#pragma unroll 8
    for (int row = 0; row < 64; ++row)
      a += wrow[row] * bf2f(Atile[row * 512 + (e ^ ((row & 7) << 3))]);
    ctxp[((size_t)b * 64 + chunk) * EE + e] = a;
  }
}

// Per b: global softmax over raw scores -> attn; combine ctx partials.
__global__ __launch_bounds__(512) void finalize_kernel(
    float* __restrict__ attn, const float* __restrict__ ctxp,
    const float* __restrict__ mbuf, float* __restrict__ ctx) {
  __shared__ float red[16];
  __shared__ float fc[64];
  int b = blockIdx.x, t = threadIdx.x;
  float* row = attn + (size_t)b * SS;
  float vals[8];
  float m = -3e38f;
#pragma unroll
  for (int i = 0; i < 8; ++i) {
    float x = row[i * 512 + t];
    vals[i] = x;
    m = fmaxf(m, x);
  }
  for (int off = 1; off < 64; off <<= 1) m = fmaxf(m, __shfl_xor(m, off, 64));
  int wv = t >> 6, ln = t & 63;
  if (ln == 0) red[wv] = m;
  __syncthreads();
  m = red[0];
#pragma unroll
  for (int i = 1; i < 8; ++i) m = fmaxf(m, red[i]);
  float sum = 0.f;
#pragma unroll
  for (int i = 0; i < 8; ++i) { vals[i] = __expf(vals[i] - m); sum += vals[i]; }
  for (int off = 1; off < 64; off <<= 1) sum += __shfl_xor(sum, off, 64);
  if (ln == 0) red[8 + wv] = sum;
  __syncthreads();
  sum = 0.f;
#pragma unroll
  for (int i = 0; i < 8; ++i) sum += red[8 + i];
  float inv = 1.f / sum;
#pragma unroll
  for (int i = 0; i < 8; ++i) row[i * 512 + t] = vals[i] * inv;

  if (t < 64) fc[t] = __expf(mbuf[b * 64 + t] - m) * inv;
  __syncthreads();
  {
    const float* p = ctxp + (size_t)b * 64 * EE + t;
    float s = 0.f;
#pragma unroll
    for (int c = 0; c < 64; ++c) s += fc[c] * p[c * EE];
    ctx[b * EE + t] = s;
  }
}

extern "C" void kernel_launch(void* const* d_in, const int* in_sizes, int n_in,
                              void* d_out, int out_size, void* d_ws, size_t ws_size,
                              hipStream_t stream) {
  const float* h    = (const float*)d_in[0];
  const float* enc  = (const float*)d_in[1];
  const int*   mask = (const int*)d_in[2];
  const float* Wh   = (const float*)d_in[3];
  const float* Ws   = (const float*)d_in[4];
  const float* v    = (const float*)d_in[5];

  float* out  = (float*)d_out;
  float* ctx  = out;              // [32,512]
  float* attn = out + BB * EE;    // [32,4096]

  char* ws = (char*)d_ws;
  float* qws = (float*)ws;                   ws += (size_t)BB * AA * 4;        // 64 KB
  unsigned short* Wst = (unsigned short*)ws; ws += (size_t)AA * EE * 2;        // 512 KB
  float* ctxp = (float*)ws;                  ws += (size_t)BB * 64 * EE * 4;   // 4 MB
  float* mbuf = (float*)ws;                  ws += (size_t)BB * 64 * 4;        // 8 KB
  unsigned short* encb = (unsigned short*)ws;                                   // 134 MB

  const size_t need = (size_t)(ws - (char*)d_ws) + (size_t)BB * SS * EE * 2;
  const int use_bf = (d_ws != nullptr && ws_size >= need) ? 1 : 0;

  hipLaunchKernelGGL(prep_kernel, dim3(use_bf ? 2144 : 96), dim3(512), 0, stream,
                     h, Wh, Ws, enc, qws, Wst, encb, use_bf);
  hipLaunchKernelGGL(fused_kernel, dim3(SS / 64, BB), dim3(512), 0, stream,
                     enc, encb, Wst, qws, v, mask, attn, ctxp, mbuf, use_bf);
  hipLaunchKernelGGL(finalize_kernel, dim3(BB), dim3(512), 0, stream,
                     attn, ctxp, mbuf, ctx);
}

// Round 6
// 520.868 us; speedup vs baseline: 1.1554x; 1.1554x over previous
//
#include <hip/hip_runtime.h>
#include <hip/hip_bf16.h>
#include <math.h>

#define BB 32
#define SS 4096
#define EE 512
#define AA 512

typedef short bf16x8 __attribute__((ext_vector_type(8)));
typedef float f32x4 __attribute__((ext_vector_type(4)));
typedef unsigned short u16x4 __attribute__((ext_vector_type(4)));

__device__ __forceinline__ unsigned short f2bf(float f) {
  unsigned int u = __float_as_uint(f);
  u += 0x7fffu + ((u >> 16) & 1u);   // RNE (finite normals)
  return (unsigned short)(u >> 16);
}

__device__ __forceinline__ float bf2f(unsigned short s) {
  return __uint_as_float(((unsigned int)s) << 16);
}

__device__ __forceinline__ float tanh_fast(float x) {
  return 1.f - 2.f / (__expf(2.f * x) + 1.f);
}

// Merged prologue, role by blockIdx.x:
//  [0,256)   : query partials. blk = b*8+sl; qpart[b*8+sl][a] =
//              sum_{e in [sl*64,sl*64+64)} h[b][e]*Wh[e][a].
//  [256,288) : WF fragment-major B-panel. nb = blk-256 (16 a-cols).
//              WF[((nb*16+kb)*64+lane)*8 + i] = bf16(Ws[kb*32+(lane>>4)*8+i]
//                                                      [nb*16+(lane&15)])
//              -> in fused, a B-fragment load is base+lane*16: ONE coalesced
//              1 KB wave-read instead of 16 lines scattered at 1 KB stride.
__global__ __launch_bounds__(512) void prep_kernel(
    const float* __restrict__ h, const float* __restrict__ Wh,
    const float* __restrict__ Ws, float* __restrict__ qpart,
    unsigned short* __restrict__ WF) {
  __shared__ float hrow[64];
  const int blk = blockIdx.x;
  const int t = threadIdx.x;
  if (blk < 256) {                      // ---- query partial ----
    const int b = blk >> 3, sl = blk & 7, e0 = sl * 64;
    if (t < 64) hrow[t] = h[b * EE + e0 + t];
    __syncthreads();
    float a = 0.f;
#pragma unroll 8
    for (int e = 0; e < 64; ++e) a += hrow[e] * Wh[(size_t)(e0 + e) * AA + t];
    qpart[(size_t)blk * AA + t] = a;
  } else {                              // ---- WF fragment-major B ----
    const int nb = blk - 256;
#pragma unroll
    for (int rep = 0; rep < 2; ++rep) {
      const int idx = rep * 512 + t;    // 0..1023 = kb*64 + lane
      const int kb = idx >> 6, lane = idx & 63;
      const int krow = kb * 32 + ((lane >> 4) << 3);
      const int acol = nb * 16 + (lane & 15);
      bf16x8 vv;
#pragma unroll
      for (int i = 0; i < 8; ++i)
        vv[i] = (short)f2bf(Ws[(size_t)(krow + i) * AA + acol]);
      ((bf16x8*)WF)[(size_t)nb * 1024 + idx] = vv;
    }
  }
}

// Fused: per block (chunk=blockIdx.x -> 64 s-rows, b=blockIdx.y), 512 threads,
// 2 blocks/CU. R1-proven pipeline (depth-1 enc prefetch, raw per-chunk barrier)
// with ONE change: B fragments come from WF (fragment-major, coalesced).
__global__ __launch_bounds__(512, 4) void fused_kernel(
    const float* __restrict__ enc, const unsigned short* __restrict__ WF,
    const float* __restrict__ qpart, const float* __restrict__ v,
    const int* __restrict__ mask,
    float* __restrict__ rawscore,   // -> attn region of d_out
    float* __restrict__ ctxp,       // [32][64][512]
    float* __restrict__ mbuf) {     // [32][64]
  __shared__ __align__(16) unsigned short Atile[64 * 512];  // 64 KB
  __shared__ float spart[8][64];
  __shared__ float wrow[64];
  const int b = blockIdx.y, chunk = blockIdx.x;
  const int s0 = chunk * 64;
  const int tid = threadIdx.x;
  const int w = tid >> 6, lane = tid & 63;
  const int quad = lane >> 4, l16 = lane & 15;
  const int n0 = w * 64;            // 8 waves x 64 N-cols

  // staging geometry (R1): rows {rbase, rbase+32}, float4 c4
  const int rbase = tid >> 4;
  const int c4 = tid & 15;
  const int sw3 = (rbase & 7) << 3;
  const float4* src4 = (const float4*)(enc + ((size_t)b * SS + s0) * EE);
  const float4* g0 = src4 + rbase * 128 + c4;
  const float4* g1 = g0 + 32 * 128;
  unsigned short* st0 = &Atile[rbase * 512 + ((c4 * 4) ^ sw3)];
  unsigned short* st1 = st0 + 32 * 512;

  // fragment-major B: lane's fragment is at (frag_idx*64 + lane)*16 bytes
  const bf16x8* wfl = (const bf16x8*)WF + lane;

  f32x4 acc[4][4];
#pragma unroll
  for (int m = 0; m < 4; ++m)
#pragma unroll
    for (int j = 0; j < 4; ++j) acc[m][j] = (f32x4){0.f, 0.f, 0.f, 0.f};

  float4 rb[2][2];
  rb[0][0] = g0[0]; rb[0][1] = g1[0];

#pragma unroll
  for (int c = 0; c < 8; ++c) {
    const int cur = c & 1;
    // convert + write chunk c
    {
      float4 x = rb[cur][0];
      u16x4 p;
      p.x = f2bf(x.x); p.y = f2bf(x.y); p.z = f2bf(x.z); p.w = f2bf(x.w);
      *(u16x4*)(st0 + c * 64) = p;
      float4 y = rb[cur][1];
      u16x4 p2;
      p2.x = f2bf(y.x); p2.y = f2bf(y.y); p2.z = f2bf(y.z); p2.w = f2bf(y.w);
      *(u16x4*)(st1 + c * 64) = p2;
    }
    // issue next-chunk enc loads; they stay in flight across the raw barrier
    if (c + 1 < 8) {
      rb[cur ^ 1][0] = g0[(c + 1) * 16];
      rb[cur ^ 1][1] = g1[(c + 1) * 16];
    }
    asm volatile("s_waitcnt lgkmcnt(0)" ::: "memory");  // ds_writes committed
    __builtin_amdgcn_s_barrier();                        // no vmcnt drain
    // ---- MFMA over k in [c*64, c*64+64) ----
#pragma unroll
    for (int kk = 0; kk < 2; ++kk) {
      const int k0 = c * 64 + kk * 32;
      bf16x8 aF[4];
#pragma unroll
      for (int m = 0; m < 4; ++m) {
        const int row = m * 16 + l16;
        aF[m] = *(const bf16x8*)&Atile[row * 512 +
                                       ((k0 + quad * 8) ^ ((row & 7) << 3))];
      }
#pragma unroll
      for (int j = 0; j < 4; ++j) {
        // frag index = nb*16 + kb, nb = w*4+j, kb = c*2+kk
        bf16x8 bF = wfl[(size_t)(((w * 4 + j) * 16 + c * 2 + kk) * 64)];
#pragma unroll
        for (int m = 0; m < 4; ++m)
          acc[m][j] = __builtin_amdgcn_mfma_f32_16x16x32_bf16(aF[m], bF,
                                                              acc[m][j], 0, 0, 0);
      }
    }
  }

  // ---- epilogue: tanh + v-weighted accumulate (q = sum of 8 partials) ----
  float srow[4][4];
#pragma unroll
  for (int m = 0; m < 4; ++m)
#pragma unroll
    for (int r = 0; r < 4; ++r) srow[m][r] = 0.f;
#pragma unroll
  for (int j = 0; j < 4; ++j) {
    const float* qp = qpart + (size_t)b * 8 * AA + n0 + j * 16 + l16;
    float qn = 0.f;
#pragma unroll
    for (int sl = 0; sl < 8; ++sl) qn += qp[sl * AA];
    float vn = v[n0 + j * 16 + l16];
#pragma unroll
    for (int m = 0; m < 4; ++m)
#pragma unroll
      for (int r = 0; r < 4; ++r)
        srow[m][r] += tanh_fast(qn + acc[m][j][r]) * vn;
  }
#pragma unroll
  for (int m = 0; m < 4; ++m)
#pragma unroll
    for (int r = 0; r < 4; ++r) {
      float s = srow[m][r];
      s += __shfl_xor(s, 1, 64);
      s += __shfl_xor(s, 2, 64);
      s += __shfl_xor(s, 4, 64);
      s += __shfl_xor(s, 8, 64);
      if (l16 == 0) spart[w][m * 16 + quad * 4 + r] = s;
    }
  __syncthreads();

  // ---- Phase C: masked scores, chunk max, exp weights ----
  if (tid < 64) {
    float raw = 0.f;
#pragma unroll
    for (int ww = 0; ww < 8; ++ww) raw += spart[ww][tid];
    float sc = mask[(size_t)b * SS + s0 + tid] ? -1e9f : raw;
    rawscore[(size_t)b * SS + s0 + tid] = sc;
    float mx = sc;
    for (int off = 1; off < 64; off <<= 1)
      mx = fmaxf(mx, __shfl_xor(mx, off, 64));
    wrow[tid] = __expf(sc - mx);
    if (tid == 0) mbuf[b * 64 + chunk] = mx;
  }
  __syncthreads();

  // ---- Phase D: ctx partial, one e-column per thread ----
  {
    const int e = tid;
    float a = 0.f;
#pragma unroll 8
    for (int row = 0; row < 64; ++row)
      a += wrow[row] * bf2f(Atile[row * 512 + (e ^ ((row & 7) << 3))]);
    ctxp[((size_t)b * 64 + chunk) * EE + e] = a;
  }
}

// Per b: global softmax over raw scores -> attn; combine ctx partials.
__global__ __launch_bounds__(512) void finalize_kernel(
    float* __restrict__ attn, const float* __restrict__ ctxp,
    const float* __restrict__ mbuf, float* __restrict__ ctx) {
  __shared__ float red[16];
  __shared__ float fc[64];
  int b = blockIdx.x, t = threadIdx.x;
  float* row = attn + (size_t)b * SS;
  float vals[8];
  float m = -3e38f;
#pragma unroll
  for (int i = 0; i < 8; ++i) {
    float x = row[i * 512 + t];
    vals[i] = x;
    m = fmaxf(m, x);
  }
  for (int off = 1; off < 64; off <<= 1) m = fmaxf(m, __shfl_xor(m, off, 64));
  int wv = t >> 6, ln = t & 63;
  if (ln == 0) red[wv] = m;
  __syncthreads();
  m = red[0];
#pragma unroll
  for (int i = 1; i < 8; ++i) m = fmaxf(m, red[i]);
  float sum = 0.f;
#pragma unroll
  for (int i = 0; i < 8; ++i) { vals[i] = __expf(vals[i] - m); sum += vals[i]; }
  for (int off = 1; off < 64; off <<= 1) sum += __shfl_xor(sum, off, 64);
  if (ln == 0) red[8 + wv] = sum;
  __syncthreads();
  sum = 0.f;
#pragma unroll
  for (int i = 0; i < 8; ++i) sum += red[8 + i];
  float inv = 1.f / sum;
#pragma unroll
  for (int i = 0; i < 8; ++i) row[i * 512 + t] = vals[i] * inv;

  if (t < 64) fc[t] = __expf(mbuf[b * 64 + t] - m) * inv;
  __syncthreads();
  {
    const float* p = ctxp + (size_t)b * 64 * EE + t;
    float s = 0.f;
#pragma unroll
    for (int c = 0; c < 64; ++c) s += fc[c] * p[c * EE];
    ctx[b * EE + t] = s;
  }
}

extern "C" void kernel_launch(void* const* d_in, const int* in_sizes, int n_in,
                              void* d_out, int out_size, void* d_ws, size_t ws_size,
                              hipStream_t stream) {
  const float* h    = (const float*)d_in[0];
  const float* enc  = (const float*)d_in[1];
  const int*   mask = (const int*)d_in[2];
  const float* Wh   = (const float*)d_in[3];
  const float* Ws   = (const float*)d_in[4];
  const float* v    = (const float*)d_in[5];

  float* out  = (float*)d_out;
  float* ctx  = out;              // [32,512]
  float* attn = out + BB * EE;    // [32,4096]

  char* ws = (char*)d_ws;
  float* qpart = (float*)ws;                 ws += (size_t)BB * 8 * AA * 4;    // 512 KB
  unsigned short* WF = (unsigned short*)ws;  ws += (size_t)AA * EE * 2;        // 512 KB
  float* ctxp = (float*)ws;                  ws += (size_t)BB * 64 * EE * 4;   // 4 MB
  float* mbuf = (float*)ws;                                                    // 8 KB

  hipLaunchKernelGGL(prep_kernel, dim3(288), dim3(512), 0, stream,
                     h, Wh, Ws, qpart, WF);
  hipLaunchKernelGGL(fused_kernel, dim3(SS / 64, BB), dim3(512), 0, stream,
                     enc, WF, qpart, v, mask, attn, ctxp, mbuf);
  hipLaunchKernelGGL(finalize_kernel, dim3(BB), dim3(512), 0, stream,
                     attn, ctxp, mbuf, ctx);
}